// Round 1
// baseline (1158.377 us; speedup 1.0000x reference)
//
#include <hip/hip_runtime.h>

#define B_   32
#define E_   512
#define HW_  256
#define S_   257
#define NH_  8
#define HD_  64
#define EC_  32
#define NCH_ (E_ / EC_)   // 16
#define NBLK 1024
#define NTHR 256
#define NWAVE (NBLK * (NTHR / 64))   // 4096

__device__ __forceinline__ float wave_reduce(float v) {
  #pragma unroll
  for (int o = 32; o > 0; o >>= 1) v += __shfl_down(v, o, 64);
  return v;
}

// Grid barrier: guaranteed-resident grid (1024 blocks @ 4 blocks/CU via launch
// bounds). Agent-scope acq_rel atomic arrive + acquire spin. On gfx950 the
// agent-scope release emits buffer_wbl2 sc1 (flush this XCD's L2 to the
// coherence point) and acquire emits buffer_inv sc1 (invalidate stale L1/L2),
// giving cross-XCD visibility of the previous phase's plain stores.
__device__ __forceinline__ void gsync(unsigned* ctr) {
  __syncthreads();                       // drains each wave's vmcnt before arrive
  if (threadIdx.x == 0) {
    __hip_atomic_fetch_add(ctr, 1u, __ATOMIC_ACQ_REL, __HIP_MEMORY_SCOPE_AGENT);
    while (__hip_atomic_load(ctr, __ATOMIC_ACQUIRE, __HIP_MEMORY_SCOPE_AGENT) < (unsigned)NBLK)
      __builtin_amdgcn_s_sleep(2);
  }
  __syncthreads();
}

__device__ void softmax257(float* l, float* red, int t) {
  float v = l[t];
  float v256 = l[256];
  red[t] = v; __syncthreads();
  #pragma unroll
  for (int s = 128; s > 0; s >>= 1) { if (t < s) red[t] = fmaxf(red[t], red[t + s]); __syncthreads(); }
  float M = fmaxf(red[0], v256);
  __syncthreads();
  float ex = expf(v - M);
  float e256 = expf(v256 - M);
  red[t] = ex; __syncthreads();
  #pragma unroll
  for (int s = 128; s > 0; s >>= 1) { if (t < s) red[t] += red[t + s]; __syncthreads(); }
  float inv = 1.f / (red[0] + e256);
  __syncthreads();
  l[t] = ex * inv;
  if (t == 0) l[256] = e256 * inv;
  __syncthreads();
}

__global__ __launch_bounds__(NTHR, 4) void k_mega(
    const float* __restrict__ xr, const float* __restrict__ xi,
    const float* __restrict__ pos_r, const float* __restrict__ pos_i,
    const float* __restrict__ w_in_r, const float* __restrict__ w_in_i,
    const float* __restrict__ b_in_r, const float* __restrict__ b_in_i,
    const float* __restrict__ w_out_r, const float* __restrict__ w_out_i,
    const float* __restrict__ b_out_r, const float* __restrict__ b_out_i,
    const float* __restrict__ w_p_r, const float* __restrict__ w_p_i,
    const float* __restrict__ b_p_r, const float* __restrict__ b_p_i,
    unsigned* bar,
    float* __restrict__ mr, float* __restrict__ mi,
    float* __restrict__ ur, float* __restrict__ ui,
    float* __restrict__ l0r, float* __restrict__ l0i,
    float* __restrict__ part, float* __restrict__ w2,
    float* __restrict__ zr_, float* __restrict__ zi_,
    float* __restrict__ a0r, float* __restrict__ a0i,
    float* __restrict__ aor, float* __restrict__ aoi,
    float* __restrict__ out, int interleaved) {
  __shared__ __align__(16) float smF[4112];   // max phase: z's 2056 float2 = 16448 B
  const int t   = threadIdx.x;
  const int l   = t & 63;
  const int w   = t >> 6;
  const int bid = blockIdx.x;
  const int gw  = bid * 4 + w;

  // ---- P1: m[b,e] = mean_s x + pos[e,0]. One float4/lane = one 256-float row/wave.
  #pragma unroll
  for (int j = 0; j < 4; ++j) {
    int task = gw + j * NWAVE;                 // [0, B*E)
    int e = task & (E_ - 1);
    float4 vr = ((const float4*)(xr + (size_t)task * HW_))[l];
    float4 vi = ((const float4*)(xi + (size_t)task * HW_))[l];
    float sr = (vr.x + vr.y) + (vr.z + vr.w);
    float si = (vi.x + vi.y) + (vi.z + vi.w);
    sr = wave_reduce(sr); si = wave_reduce(si);
    if (l == 0) {
      mr[task] = sr * (1.f / HW_) + pos_r[(size_t)e * S_];
      mi[task] = si * (1.f / HW_) + pos_i[(size_t)e * S_];
    }
  }
  gsync(bar + 0);

  // ---- P2: q0 (LDS-only) -> u[b,h,e] -> l0[b,h] = X0 . u  (fused k_q0+k_u+p0) ----
  if (bid < B_ * NH_) {
    int b = bid >> 3, h = bid & 7;
    float* mR  = smF;          // 512
    float* mI  = smF + 512;    // 512
    float* q0R = smF + 1024;   // 64
    float* q0I = smF + 1088;   // 64
    float* red = smF + 1152;   // 256
    mR[t]       = mr[b * E_ + t];        mI[t]       = mi[b * E_ + t];
    mR[t + 256] = mr[b * E_ + t + 256];  mI[t + 256] = mi[b * E_ + t + 256];
    __syncthreads();
    // q0[d]: wave w owns d = w*16 + j2, lanes stride e (coalesced weight rows)
    for (int j2 = 0; j2 < 16; ++j2) {
      int d = w * 16 + j2;
      int f = h * HD_ + d;
      const float* wr = w_in_r + (size_t)f * E_;
      const float* wi = w_in_i + (size_t)f * E_;
      float ar = 0.f, ai = 0.f;
      #pragma unroll
      for (int e = l; e < E_; e += 64) {
        float Xr = mR[e], Xi = mI[e], Cr = wr[e], Ci = wi[e];
        ar += Xr * Cr - Xi * Ci;
        ai += Xr * Ci + Xi * Cr;
      }
      ar = wave_reduce(ar); ai = wave_reduce(ai);
      if (l == 0) {
        q0R[d] = (ar + b_in_r[f]) * 0.125f;
        q0I[d] = (ai + b_in_i[f]) * 0.125f;
      }
    }
    __syncthreads();
    // u: thread owns e = t and t+256 (coalesced across threads per d)
    float u0r = 0.f, u0i = 0.f, u1r = 0.f, u1i = 0.f;
    #pragma unroll 8
    for (int d = 0; d < HD_; ++d) {
      float qr = q0R[d], qi = q0I[d];
      const float* Wr = w_in_r + (size_t)(E_ + h * HD_ + d) * E_;
      const float* Wi = w_in_i + (size_t)(E_ + h * HD_ + d) * E_;
      float W0r = Wr[t], W0i = Wi[t], W1r = Wr[t + 256], W1i = Wi[t + 256];
      u0r += qr * W0r - qi * W0i;  u0i += qr * W0i + qi * W0r;
      u1r += qr * W1r - qi * W1i;  u1i += qr * W1i + qi * W1r;
    }
    ur[(size_t)bid * E_ + t]       = u0r;  ui[(size_t)bid * E_ + t]       = u0i;
    ur[(size_t)bid * E_ + t + 256] = u1r;  ui[(size_t)bid * E_ + t + 256] = u1i;
    // l0 = sum_e X0 * u  (mean-token logit, removes two tree-reduces from P4)
    float pr = mR[t] * u0r - mI[t] * u0i + mR[t + 256] * u1r - mI[t + 256] * u1i;
    float pi = mR[t] * u0i + mI[t] * u0r + mR[t + 256] * u1i + mI[t + 256] * u1r;
    red[t] = pr; __syncthreads();
    #pragma unroll
    for (int s = 128; s > 0; s >>= 1) { if (t < s) red[t] += red[t + s]; __syncthreads(); }
    if (t == 0) l0r[bid] = red[0];
    __syncthreads();
    red[t] = pi; __syncthreads();
    #pragma unroll
    for (int s = 128; s > 0; s >>= 1) { if (t < s) red[t] += red[t + s]; __syncthreads(); }
    if (t == 0) l0i[bid] = red[0];
  }
  gsync(bar + 1);

  // ---- P3: partial logits over e-chunks (k_logits body) ----
  if (bid < B_ * NCH_) {
    int b = bid / NCH_, c = bid % NCH_;
    int e0 = c * EC_;
    float* us = smF;                            // [32][8][2] = 512 floats
    { int e = t >> 3, hh = t & 7;
      us[(e * 8 + hh) * 2 + 0] = ur[(size_t)(b * NH_ + hh) * E_ + e0 + e];
      us[(e * 8 + hh) * 2 + 1] = ui[(size_t)(b * NH_ + hh) * E_ + e0 + e]; }
    __syncthreads();
    float ar[NH_], ai[NH_];
    #pragma unroll
    for (int hh = 0; hh < NH_; ++hh) { ar[hh] = 0.f; ai[hh] = 0.f; }
    const float* xrb = xr + ((size_t)b * E_ + e0) * HW_;
    const float* xib = xi + ((size_t)b * E_ + e0) * HW_;
    #pragma unroll 2
    for (int e = 0; e < EC_; ++e) {
      float Xr = xrb[e * HW_ + t] + pos_r[(size_t)(e0 + e) * S_ + t + 1];
      float Xi = xib[e * HW_ + t] + pos_i[(size_t)(e0 + e) * S_ + t + 1];
      #pragma unroll
      for (int hh = 0; hh < NH_; ++hh) {
        float Ur = us[(e * 8 + hh) * 2 + 0], Ui = us[(e * 8 + hh) * 2 + 1];
        ar[hh] += Xr * Ur - Xi * Ui;
        ai[hh] += Xr * Ui + Xi * Ur;
      }
    }
    float2* p2 = (float2*)part;
    #pragma unroll
    for (int hh = 0; hh < NH_; ++hh) {
      float2 v; v.x = ar[hh]; v.y = ai[hh];
      p2[((size_t)(b * NH_ + hh) * NCH_ + c) * 256 + t] = v;
    }
  }
  gsync(bar + 2);

  // ---- P4: reduce partials + l0 + dual softmax -> w2 ----
  if (bid < B_ * NH_) {
    int bh = bid;
    float* lr  = smF;          // 257
    float* li  = smF + 260;    // 257
    float* red = smF + 520;    // 256
    const float2* p2 = (const float2*)part + (size_t)bh * NCH_ * 256;
    float sr = 0.f, si = 0.f;
    #pragma unroll
    for (int c = 0; c < NCH_; ++c) { float2 v = p2[c * 256 + t]; sr += v.x; si += v.y; }
    lr[t + 1] = sr; li[t + 1] = si;
    if (t == 0) { lr[0] = l0r[bh]; li[0] = l0i[bh]; }
    __syncthreads();
    softmax257(lr, red, t);
    softmax257(li, red, t);
    float2* o = (float2*)w2 + (size_t)bh * S_;
    float2 v; v.x = lr[t]; v.y = li[t]; o[t] = v;
    if (t == 0) { float2 v2; v2.x = lr[256]; v2.y = li[256]; o[256] = v2; }
  }
  gsync(bar + 3);

  // ---- P5: z[b,h,e] = sum_k w[b,h,k] X[b,k,e]. Block owns (b, gg) and (b, gg+32)
  //      so the 16.4 KB w-LDS tile loads once per block. ----
  {
    int b = bid >> 5, gg = bid & 31;
    float2* wls = (float2*)smF;                 // 2056 float2
    const float2* w2b = (const float2*)w2 + (size_t)b * NH_ * S_;
    for (int i = t; i < NH_ * S_; i += NTHR) wls[i] = w2b[i];
    __syncthreads();
    #pragma unroll
    for (int sub = 0; sub < 2; ++sub) {
      int g = gg + sub * 32;
      #pragma unroll
      for (int r = 0; r < 2; ++r) {
        int e = g * 8 + w * 2 + r;
        const float* xre = xr + ((size_t)b * E_ + e) * HW_;
        const float* xie = xi + ((size_t)b * E_ + e) * HW_;
        const float* pre = pos_r + (size_t)e * S_;
        const float* pie = pos_i + (size_t)e * S_;
        float ar2[NH_], ai2[NH_];
        #pragma unroll
        for (int hh = 0; hh < NH_; ++hh) { ar2[hh] = 0.f; ai2[hh] = 0.f; }
        #pragma unroll
        for (int j = 0; j < 4; ++j) {
          int k = 1 + l + 64 * j;
          float Xr = xre[k - 1] + pre[k];
          float Xi = xie[k - 1] + pie[k];
          #pragma unroll
          for (int hh = 0; hh < NH_; ++hh) {
            float2 W = wls[hh * S_ + k];
            ar2[hh] += W.x * Xr - W.y * Xi;
            ai2[hh] += W.x * Xi + W.y * Xr;
          }
        }
        #pragma unroll
        for (int hh = 0; hh < NH_; ++hh) { ar2[hh] = wave_reduce(ar2[hh]); ai2[hh] = wave_reduce(ai2[hh]); }
        if (l == 0) {
          float X0r = mr[b * E_ + e];
          float X0i = mi[b * E_ + e];
          #pragma unroll
          for (int hh = 0; hh < NH_; ++hh) {
            float2 W0 = wls[hh * S_];
            zr_[(size_t)(b * NH_ + hh) * E_ + e] = ar2[hh] + W0.x * X0r - W0.y * X0i;
            zi_[(size_t)(b * NH_ + hh) * E_ + e] = ai2[hh] + W0.x * X0i + W0.y * X0r;
          }
        }
      }
    }
  }
  gsync(bar + 4);

  // ---- P6: attn0[b,f] = w_v[f,:] . z[b,h(f),:] + b_v[f]*(1+i) ----
  #pragma unroll
  for (int j = 0; j < 4; ++j) {
    int wid = gw + j * NWAVE;
    int b = wid >> 9, f = wid & (E_ - 1);
    int h = f >> 6;
    const float* wrp = w_in_r + (size_t)(2 * E_ + f) * E_;
    const float* wip = w_in_i + (size_t)(2 * E_ + f) * E_;
    const float* zrp = zr_ + (size_t)(b * NH_ + h) * E_;
    const float* zip = zi_ + (size_t)(b * NH_ + h) * E_;
    float ar = 0.f, ai = 0.f;
    #pragma unroll
    for (int e = l; e < E_; e += 64) {
      float Zr = zrp[e], Zi = zip[e], Cr = wrp[e], Ci = wip[e];
      ar += Zr * Cr - Zi * Ci;
      ai += Zr * Ci + Zi * Cr;
    }
    ar = wave_reduce(ar); ai = wave_reduce(ai);
    if (l == 0) {
      float bvr = b_in_r[2 * E_ + f], bvi = b_in_i[2 * E_ + f];
      a0r[wid] = ar + (bvr - bvi);   // sum of complex softmax weights = 1 + i
      a0i[wid] = ai + (bvr + bvi);
    }
  }
  gsync(bar + 5);

  // ---- P7: out-proj: ao[b,f] = a0[b,:] . w_out[f,:] + b_out[f] ----
  #pragma unroll
  for (int j = 0; j < 4; ++j) {
    int wid = gw + j * NWAVE;
    int b = wid >> 9, f = wid & (E_ - 1);
    const float* wrp = w_out_r + (size_t)f * E_;
    const float* wip = w_out_i + (size_t)f * E_;
    const float* ir = a0r + (size_t)b * E_;
    const float* ii = a0i + (size_t)b * E_;
    float ar = 0.f, ai = 0.f;
    #pragma unroll
    for (int e = l; e < E_; e += 64) {
      float Xr = ir[e], Xi = ii[e], Cr = wrp[e], Ci = wip[e];
      ar += Xr * Cr - Xi * Ci;
      ai += Xr * Ci + Xi * Cr;
    }
    ar = wave_reduce(ar); ai = wave_reduce(ai);
    if (l == 0) { aor[wid] = ar + b_out_r[f]; aoi[wid] = ai + b_out_i[f]; }
  }
  gsync(bar + 6);

  // ---- P8: final projection, interleaved complex64 out ----
  #pragma unroll
  for (int j = 0; j < 4; ++j) {
    int wid = gw + j * NWAVE;
    int b = wid >> 9, f = wid & (E_ - 1);
    const float* wrp = w_p_r + (size_t)f * E_;
    const float* wip = w_p_i + (size_t)f * E_;
    const float* ir = aor + (size_t)b * E_;
    const float* ii = aoi + (size_t)b * E_;
    float ar = 0.f, ai = 0.f;
    #pragma unroll
    for (int e = l; e < E_; e += 64) {
      float Xr = ir[e], Xi = ii[e], Cr = wrp[e], Ci = wip[e];
      ar += Xr * Cr - Xi * Ci;
      ai += Xr * Ci + Xi * Cr;
    }
    ar = wave_reduce(ar); ai = wave_reduce(ai);
    if (l == 0) {
      float rr = ar + b_p_r[f];
      float im = ai + b_p_i[f];
      if (interleaved) { out[(size_t)wid * 2] = rr; out[(size_t)wid * 2 + 1] = im; }
      else             { out[wid] = rr; }
    }
  }
}

extern "C" void kernel_launch(void* const* d_in, const int* in_sizes, int n_in,
                              void* d_out, int out_size, void* d_ws, size_t ws_size,
                              hipStream_t stream) {
  (void)in_sizes; (void)n_in; (void)ws_size;
  const float* xr      = (const float*)d_in[0];
  const float* xi      = (const float*)d_in[1];
  const float* pos_r   = (const float*)d_in[2];
  const float* pos_i   = (const float*)d_in[3];
  const float* w_in_r  = (const float*)d_in[4];
  const float* w_in_i  = (const float*)d_in[5];
  const float* b_in_r  = (const float*)d_in[6];
  const float* b_in_i  = (const float*)d_in[7];
  const float* w_out_r = (const float*)d_in[8];
  const float* w_out_i = (const float*)d_in[9];
  const float* b_out_r = (const float*)d_in[10];
  const float* b_out_i = (const float*)d_in[11];
  const float* w_p_r   = (const float*)d_in[12];
  const float* w_p_i   = (const float*)d_in[13];
  const float* b_p_r   = (const float*)d_in[14];
  const float* b_p_i   = (const float*)d_in[15];

  const int BE = B_ * E_, BHE = B_ * NH_ * E_;
  float*    ws  = (float*)d_ws;
  unsigned* bar = (unsigned*)d_ws;               // 7 barrier counters in first 256 B
  float* mr   = ws + 64;
  float* mi   = mr  + BE;
  float* ur   = mi  + BE;
  float* ui   = ur  + BHE;
  float* l0r  = ui  + BHE;
  float* l0i  = l0r + B_ * NH_;
  float* part = l0i + B_ * NH_;                  // B*NH*NCH*256*2 floats
  float* w2   = part + (size_t)B_ * NH_ * NCH_ * 512;
  float* zr   = w2  + (size_t)2 * B_ * NH_ * S_;
  float* zi   = zr  + BHE;
  float* a0r  = zi  + BHE;
  float* a0i  = a0r + BE;
  float* aor  = a0i + BE;
  float* aoi  = aor + BE;

  // ws is re-poisoned every iteration -> zero the barrier counters in-graph.
  hipMemsetAsync(d_ws, 0, 256, stream);
  k_mega<<<NBLK, NTHR, 0, stream>>>(
      xr, xi, pos_r, pos_i, w_in_r, w_in_i, b_in_r, b_in_i,
      w_out_r, w_out_i, b_out_r, b_out_i, w_p_r, w_p_i, b_p_r, b_p_i,
      bar, mr, mi, ur, ui, l0r, l0i, part, w2, zr, zi, a0r, a0i, aor, aoi,
      (float*)d_out, out_size >= 2 * B_ * E_);
}

// Round 3
// 196.925 us; speedup vs baseline: 5.8823x; 5.8823x over previous
//
#include <hip/hip_runtime.h>

#define B_   32
#define E_   512
#define HW_  256
#define S_   257
#define NH_  8
#define HD_  64
#define EC_  32
#define NCH_ (E_ / EC_)   // 16
#define NBLK 1024
#define NTHR 256
#define NWAVE (NBLK * (NTHR / 64))   // 4096
#define NGRP 32
#define GSZ  32
#define BAR_STRIDE 2080   // uints per barrier: 32*32 gcnt + 32 gctr + 32*32 gflag

// ---- write-through stores (sc0 sc1): land at the coherence point (IF/L3).
// Intermediates are written ONCE and read only after a barrier (first touch),
// so readers can never hold a stale L2 copy -> barriers need no buffer_inv /
// buffer_wbl2 at all (round-1's 145us/barrier was the acquire-poll inv storm).
__device__ __forceinline__ void st_sys(float* p, float v) {
  __hip_atomic_store(p, v, __ATOMIC_RELAXED, __HIP_MEMORY_SCOPE_SYSTEM);
}
__device__ __forceinline__ void st_sys2(float2* p, float2 v) {
  unsigned long long u;
  __builtin_memcpy(&u, &v, 8);
  __hip_atomic_store((unsigned long long*)p, u, __ATOMIC_RELAXED, __HIP_MEMORY_SCOPE_SYSTEM);
}

__device__ __forceinline__ float wave_reduce(float v) {
  #pragma unroll
  for (int o = 32; o > 0; o >>= 1) v += __shfl_down(v, o, 64);
  return v;
}

// Hierarchical grid barrier, zero cache-maintenance ops:
//  - arrive: relaxed agent fetch_add on per-group line (32 blocks/line),
//    last-of-group bumps the single global line (32 RMWs), last leader
//    broadcasts 32 per-group release flags (write-through stores).
//  - poll: SYSTEM-scope relaxed load (sc0 sc1 -> always reads the coherence
//    point; cannot spin forever on a stale XCD-L2 line, which is the round-2
//    hang mechanism for agent-relaxed polls).
// __syncthreads() before the arrive drains vmcnt, so all of this block's
// write-through stores are performed at the coherence point before its
// arrival is observable.
__device__ __forceinline__ void gsync(unsigned* base, int bid, int t) {
  __syncthreads();
  if (t == 0) {
    int g = bid >> 5;
    unsigned* gcnt  = base + g * 32;
    unsigned* gctr  = base + NGRP * 32;
    unsigned* gflag = base + (NGRP + 1) * 32 + g * 32;
    if (__hip_atomic_fetch_add(gcnt, 1u, __ATOMIC_RELAXED, __HIP_MEMORY_SCOPE_AGENT) == GSZ - 1) {
      if (__hip_atomic_fetch_add(gctr, 1u, __ATOMIC_RELAXED, __HIP_MEMORY_SCOPE_AGENT) == NGRP - 1) {
        #pragma unroll
        for (int i = 0; i < NGRP; ++i)
          __hip_atomic_store(base + (NGRP + 1) * 32 + i * 32, 1u,
                             __ATOMIC_RELAXED, __HIP_MEMORY_SCOPE_SYSTEM);
      }
    }
    while (__hip_atomic_load(gflag, __ATOMIC_RELAXED, __HIP_MEMORY_SCOPE_SYSTEM) == 0u)
      __builtin_amdgcn_s_sleep(8);
  }
  __syncthreads();
}

__device__ void softmax257(float* l, float* red, int t) {
  float v = l[t];
  float v256 = l[256];
  red[t] = v; __syncthreads();
  #pragma unroll
  for (int s = 128; s > 0; s >>= 1) { if (t < s) red[t] = fmaxf(red[t], red[t + s]); __syncthreads(); }
  float M = fmaxf(red[0], v256);
  __syncthreads();
  float ex = expf(v - M);
  float e256 = expf(v256 - M);
  red[t] = ex; __syncthreads();
  #pragma unroll
  for (int s = 128; s > 0; s >>= 1) { if (t < s) red[t] += red[t + s]; __syncthreads(); }
  float inv = 1.f / (red[0] + e256);
  __syncthreads();
  l[t] = ex * inv;
  if (t == 0) l[256] = e256 * inv;
  __syncthreads();
}

__global__ __launch_bounds__(NTHR, 4) void k_mega(
    const float* __restrict__ xr, const float* __restrict__ xi,
    const float* __restrict__ pos_r, const float* __restrict__ pos_i,
    const float* __restrict__ w_in_r, const float* __restrict__ w_in_i,
    const float* __restrict__ b_in_r, const float* __restrict__ b_in_i,
    const float* __restrict__ w_out_r, const float* __restrict__ w_out_i,
    const float* __restrict__ b_out_r, const float* __restrict__ b_out_i,
    const float* __restrict__ w_p_r, const float* __restrict__ w_p_i,
    const float* __restrict__ b_p_r, const float* __restrict__ b_p_i,
    unsigned* bar,
    float* __restrict__ mr, float* __restrict__ mi,
    float* __restrict__ ur, float* __restrict__ ui,
    float* __restrict__ l0r, float* __restrict__ l0i,
    float* __restrict__ part, float* __restrict__ w2,
    float* __restrict__ zr_, float* __restrict__ zi_,
    float* __restrict__ a0r, float* __restrict__ a0i,
    float* __restrict__ aor, float* __restrict__ aoi,
    float* __restrict__ out, int interleaved) {
  __shared__ __align__(16) float smF[4112];   // max phase: z's 2056 float2 = 16448 B
  const int t   = threadIdx.x;
  const int l   = t & 63;
  const int w   = t >> 6;
  const int bid = blockIdx.x;
  const int gw  = bid * 4 + w;

  // ---- P1: m[b,e] = mean_s x + pos[e,0]. One float4/lane = one 256-float row/wave.
  #pragma unroll
  for (int j = 0; j < 4; ++j) {
    int task = gw + j * NWAVE;                 // [0, B*E)
    int e = task & (E_ - 1);
    float4 vr = ((const float4*)(xr + (size_t)task * HW_))[l];
    float4 vi = ((const float4*)(xi + (size_t)task * HW_))[l];
    float sr = (vr.x + vr.y) + (vr.z + vr.w);
    float si = (vi.x + vi.y) + (vi.z + vi.w);
    sr = wave_reduce(sr); si = wave_reduce(si);
    if (l == 0) {
      st_sys(&mr[task], sr * (1.f / HW_) + pos_r[(size_t)e * S_]);
      st_sys(&mi[task], si * (1.f / HW_) + pos_i[(size_t)e * S_]);
    }
  }
  gsync(bar + 0 * BAR_STRIDE, bid, t);

  // ---- P2: q0 (LDS-only) -> u[b,h,e] -> l0[b,h] = X0 . u  (fused k_q0+k_u+p0) ----
  if (bid < B_ * NH_) {
    int b = bid >> 3, h = bid & 7;
    float* mR  = smF;          // 512
    float* mI  = smF + 512;    // 512
    float* q0R = smF + 1024;   // 64
    float* q0I = smF + 1088;   // 64
    float* red = smF + 1152;   // 256
    mR[t]       = mr[b * E_ + t];        mI[t]       = mi[b * E_ + t];
    mR[t + 256] = mr[b * E_ + t + 256];  mI[t + 256] = mi[b * E_ + t + 256];
    __syncthreads();
    // q0[d]: wave w owns d = w*16 + j2, lanes stride e (coalesced weight rows)
    for (int j2 = 0; j2 < 16; ++j2) {
      int d = w * 16 + j2;
      int f = h * HD_ + d;
      const float* wr = w_in_r + (size_t)f * E_;
      const float* wi = w_in_i + (size_t)f * E_;
      float ar = 0.f, ai = 0.f;
      #pragma unroll
      for (int e = l; e < E_; e += 64) {
        float Xr = mR[e], Xi = mI[e], Cr = wr[e], Ci = wi[e];
        ar += Xr * Cr - Xi * Ci;
        ai += Xr * Ci + Xi * Cr;
      }
      ar = wave_reduce(ar); ai = wave_reduce(ai);
      if (l == 0) {
        q0R[d] = (ar + b_in_r[f]) * 0.125f;
        q0I[d] = (ai + b_in_i[f]) * 0.125f;
      }
    }
    __syncthreads();
    // u: thread owns e = t and t+256 (coalesced across threads per d)
    float u0r = 0.f, u0i = 0.f, u1r = 0.f, u1i = 0.f;
    #pragma unroll 8
    for (int d = 0; d < HD_; ++d) {
      float qr = q0R[d], qi = q0I[d];
      const float* Wr = w_in_r + (size_t)(E_ + h * HD_ + d) * E_;
      const float* Wi = w_in_i + (size_t)(E_ + h * HD_ + d) * E_;
      float W0r = Wr[t], W0i = Wi[t], W1r = Wr[t + 256], W1i = Wi[t + 256];
      u0r += qr * W0r - qi * W0i;  u0i += qr * W0i + qi * W0r;
      u1r += qr * W1r - qi * W1i;  u1i += qr * W1i + qi * W1r;
    }
    st_sys(&ur[(size_t)bid * E_ + t], u0r);        st_sys(&ui[(size_t)bid * E_ + t], u0i);
    st_sys(&ur[(size_t)bid * E_ + t + 256], u1r);  st_sys(&ui[(size_t)bid * E_ + t + 256], u1i);
    // l0 = sum_e X0 * u  (mean-token logit, removes two tree-reduces from P4)
    float pr = mR[t] * u0r - mI[t] * u0i + mR[t + 256] * u1r - mI[t + 256] * u1i;
    float pi = mR[t] * u0i + mI[t] * u0r + mR[t + 256] * u1i + mI[t + 256] * u1r;
    red[t] = pr; __syncthreads();
    #pragma unroll
    for (int s = 128; s > 0; s >>= 1) { if (t < s) red[t] += red[t + s]; __syncthreads(); }
    if (t == 0) st_sys(&l0r[bid], red[0]);
    __syncthreads();
    red[t] = pi; __syncthreads();
    #pragma unroll
    for (int s = 128; s > 0; s >>= 1) { if (t < s) red[t] += red[t + s]; __syncthreads(); }
    if (t == 0) st_sys(&l0i[bid], red[0]);
  }
  gsync(bar + 1 * BAR_STRIDE, bid, t);

  // ---- P3: partial logits over e-chunks (k_logits body) ----
  if (bid < B_ * NCH_) {
    int b = bid / NCH_, c = bid % NCH_;
    int e0 = c * EC_;
    float* us = smF;                            // [32][8][2] = 512 floats
    { int e = t >> 3, hh = t & 7;
      us[(e * 8 + hh) * 2 + 0] = ur[(size_t)(b * NH_ + hh) * E_ + e0 + e];
      us[(e * 8 + hh) * 2 + 1] = ui[(size_t)(b * NH_ + hh) * E_ + e0 + e]; }
    __syncthreads();
    float ar[NH_], ai[NH_];
    #pragma unroll
    for (int hh = 0; hh < NH_; ++hh) { ar[hh] = 0.f; ai[hh] = 0.f; }
    const float* xrb = xr + ((size_t)b * E_ + e0) * HW_;
    const float* xib = xi + ((size_t)b * E_ + e0) * HW_;
    #pragma unroll 2
    for (int e = 0; e < EC_; ++e) {
      float Xr = xrb[e * HW_ + t] + pos_r[(size_t)(e0 + e) * S_ + t + 1];
      float Xi = xib[e * HW_ + t] + pos_i[(size_t)(e0 + e) * S_ + t + 1];
      #pragma unroll
      for (int hh = 0; hh < NH_; ++hh) {
        float Ur = us[(e * 8 + hh) * 2 + 0], Ui = us[(e * 8 + hh) * 2 + 1];
        ar[hh] += Xr * Ur - Xi * Ui;
        ai[hh] += Xr * Ui + Xi * Ur;
      }
    }
    float2* p2 = (float2*)part;
    #pragma unroll
    for (int hh = 0; hh < NH_; ++hh) {
      float2 v; v.x = ar[hh]; v.y = ai[hh];
      st_sys2(&p2[((size_t)(b * NH_ + hh) * NCH_ + c) * 256 + t], v);
    }
  }
  gsync(bar + 2 * BAR_STRIDE, bid, t);

  // ---- P4: reduce partials + l0 + dual softmax -> w2 ----
  if (bid < B_ * NH_) {
    int bh = bid;
    float* lr  = smF;          // 257
    float* li  = smF + 260;    // 257
    float* red = smF + 520;    // 256
    const float2* p2 = (const float2*)part + (size_t)bh * NCH_ * 256;
    float sr = 0.f, si = 0.f;
    #pragma unroll
    for (int c = 0; c < NCH_; ++c) { float2 v = p2[c * 256 + t]; sr += v.x; si += v.y; }
    lr[t + 1] = sr; li[t + 1] = si;
    if (t == 0) { lr[0] = l0r[bh]; li[0] = l0i[bh]; }
    __syncthreads();
    softmax257(lr, red, t);
    softmax257(li, red, t);
    float2* o = (float2*)w2 + (size_t)bh * S_;
    float2 v; v.x = lr[t]; v.y = li[t];
    st_sys2(&o[t], v);
    if (t == 0) { float2 v2; v2.x = lr[256]; v2.y = li[256]; st_sys2(&o[256], v2); }
  }
  gsync(bar + 3 * BAR_STRIDE, bid, t);

  // ---- P5: z[b,h,e] = sum_k w[b,h,k] X[b,k,e]. Block owns (b, gg) and (b, gg+32)
  //      so the 16.4 KB w-LDS tile loads once per block. ----
  {
    int b = bid >> 5, gg = bid & 31;
    float2* wls = (float2*)smF;                 // 2056 float2
    const float2* w2b = (const float2*)w2 + (size_t)b * NH_ * S_;
    for (int i = t; i < NH_ * S_; i += NTHR) wls[i] = w2b[i];
    __syncthreads();
    #pragma unroll
    for (int sub = 0; sub < 2; ++sub) {
      int g = gg + sub * 32;
      #pragma unroll
      for (int r = 0; r < 2; ++r) {
        int e = g * 8 + w * 2 + r;
        const float* xre = xr + ((size_t)b * E_ + e) * HW_;
        const float* xie = xi + ((size_t)b * E_ + e) * HW_;
        const float* pre = pos_r + (size_t)e * S_;
        const float* pie = pos_i + (size_t)e * S_;
        float ar2[NH_], ai2[NH_];
        #pragma unroll
        for (int hh = 0; hh < NH_; ++hh) { ar2[hh] = 0.f; ai2[hh] = 0.f; }
        #pragma unroll
        for (int j = 0; j < 4; ++j) {
          int k = 1 + l + 64 * j;
          float Xr = xre[k - 1] + pre[k];
          float Xi = xie[k - 1] + pie[k];
          #pragma unroll
          for (int hh = 0; hh < NH_; ++hh) {
            float2 W = wls[hh * S_ + k];
            ar2[hh] += W.x * Xr - W.y * Xi;
            ai2[hh] += W.x * Xi + W.y * Xr;
          }
        }
        #pragma unroll
        for (int hh = 0; hh < NH_; ++hh) { ar2[hh] = wave_reduce(ar2[hh]); ai2[hh] = wave_reduce(ai2[hh]); }
        if (l == 0) {
          float X0r = mr[b * E_ + e];
          float X0i = mi[b * E_ + e];
          #pragma unroll
          for (int hh = 0; hh < NH_; ++hh) {
            float2 W0 = wls[hh * S_];
            st_sys(&zr_[(size_t)(b * NH_ + hh) * E_ + e], ar2[hh] + W0.x * X0r - W0.y * X0i);
            st_sys(&zi_[(size_t)(b * NH_ + hh) * E_ + e], ai2[hh] + W0.x * X0i + W0.y * X0r);
          }
        }
      }
    }
  }
  gsync(bar + 4 * BAR_STRIDE, bid, t);

  // ---- P6: attn0[b,f] = w_v[f,:] . z[b,h(f),:] + b_v[f]*(1+i) ----
  #pragma unroll
  for (int j = 0; j < 4; ++j) {
    int wid = gw + j * NWAVE;
    int b = wid >> 9, f = wid & (E_ - 1);
    int h = f >> 6;
    const float* wrp = w_in_r + (size_t)(2 * E_ + f) * E_;
    const float* wip = w_in_i + (size_t)(2 * E_ + f) * E_;
    const float* zrp = zr_ + (size_t)(b * NH_ + h) * E_;
    const float* zip = zi_ + (size_t)(b * NH_ + h) * E_;
    float ar = 0.f, ai = 0.f;
    #pragma unroll
    for (int e = l; e < E_; e += 64) {
      float Zr = zrp[e], Zi = zip[e], Cr = wrp[e], Ci = wip[e];
      ar += Zr * Cr - Zi * Ci;
      ai += Zr * Ci + Zi * Cr;
    }
    ar = wave_reduce(ar); ai = wave_reduce(ai);
    if (l == 0) {
      float bvr = b_in_r[2 * E_ + f], bvi = b_in_i[2 * E_ + f];
      st_sys(&a0r[wid], ar + (bvr - bvi));   // sum of complex softmax weights = 1 + i
      st_sys(&a0i[wid], ai + (bvr + bvi));
    }
  }
  gsync(bar + 5 * BAR_STRIDE, bid, t);

  // ---- P7: out-proj: ao[b,f] = a0[b,:] . w_out[f,:] + b_out[f] ----
  #pragma unroll
  for (int j = 0; j < 4; ++j) {
    int wid = gw + j * NWAVE;
    int b = wid >> 9, f = wid & (E_ - 1);
    const float* wrp = w_out_r + (size_t)f * E_;
    const float* wip = w_out_i + (size_t)f * E_;
    const float* ir = a0r + (size_t)b * E_;
    const float* ii = a0i + (size_t)b * E_;
    float ar = 0.f, ai = 0.f;
    #pragma unroll
    for (int e = l; e < E_; e += 64) {
      float Xr = ir[e], Xi = ii[e], Cr = wrp[e], Ci = wip[e];
      ar += Xr * Cr - Xi * Ci;
      ai += Xr * Ci + Xi * Cr;
    }
    ar = wave_reduce(ar); ai = wave_reduce(ai);
    if (l == 0) { st_sys(&aor[wid], ar + b_out_r[f]); st_sys(&aoi[wid], ai + b_out_i[f]); }
  }
  gsync(bar + 6 * BAR_STRIDE, bid, t);

  // ---- P8: final projection, interleaved complex64 out (plain stores; CP
  //      writeback-invalidate at dispatch end makes them host-visible) ----
  #pragma unroll
  for (int j = 0; j < 4; ++j) {
    int wid = gw + j * NWAVE;
    int b = wid >> 9, f = wid & (E_ - 1);
    const float* wrp = w_p_r + (size_t)f * E_;
    const float* wip = w_p_i + (size_t)f * E_;
    const float* ir = aor + (size_t)b * E_;
    const float* ii = aoi + (size_t)b * E_;
    float ar = 0.f, ai = 0.f;
    #pragma unroll
    for (int e = l; e < E_; e += 64) {
      float Xr = ir[e], Xi = ii[e], Cr = wrp[e], Ci = wip[e];
      ar += Xr * Cr - Xi * Ci;
      ai += Xr * Ci + Xi * Cr;
    }
    ar = wave_reduce(ar); ai = wave_reduce(ai);
    if (l == 0) {
      float rr = ar + b_p_r[f];
      float im = ai + b_p_i[f];
      if (interleaved) { out[(size_t)wid * 2] = rr; out[(size_t)wid * 2 + 1] = im; }
      else             { out[wid] = rr; }
    }
  }
}

extern "C" void kernel_launch(void* const* d_in, const int* in_sizes, int n_in,
                              void* d_out, int out_size, void* d_ws, size_t ws_size,
                              hipStream_t stream) {
  (void)in_sizes; (void)n_in; (void)ws_size;
  const float* xr      = (const float*)d_in[0];
  const float* xi      = (const float*)d_in[1];
  const float* pos_r   = (const float*)d_in[2];
  const float* pos_i   = (const float*)d_in[3];
  const float* w_in_r  = (const float*)d_in[4];
  const float* w_in_i  = (const float*)d_in[5];
  const float* b_in_r  = (const float*)d_in[6];
  const float* b_in_i  = (const float*)d_in[7];
  const float* w_out_r = (const float*)d_in[8];
  const float* w_out_i = (const float*)d_in[9];
  const float* b_out_r = (const float*)d_in[10];
  const float* b_out_i = (const float*)d_in[11];
  const float* w_p_r   = (const float*)d_in[12];
  const float* w_p_i   = (const float*)d_in[13];
  const float* b_p_r   = (const float*)d_in[14];
  const float* b_p_i   = (const float*)d_in[15];

  const int BE = B_ * E_, BHE = B_ * NH_ * E_;
  unsigned* bar = (unsigned*)d_ws;               // 7 barriers x 2080 uints = 58 KB
  float* base = (float*)d_ws + 16384;            // data region starts at +64 KB
  float* mr   = base;
  float* mi   = mr  + BE;
  float* ur   = mi  + BE;
  float* ui   = ur  + BHE;
  float* l0r  = ui  + BHE;
  float* l0i  = l0r + B_ * NH_;
  float* part = l0i + B_ * NH_;                  // B*NH*NCH*256*2 floats
  float* w2   = part + (size_t)B_ * NH_ * NCH_ * 512;
  float* zr   = w2  + (size_t)2 * B_ * NH_ * S_;
  float* zi   = zr  + BHE;
  float* a0r  = zi  + BHE;
  float* a0i  = a0r + BE;
  float* aor  = a0i + BE;
  float* aoi  = aor + BE;

  // ws is re-poisoned every iteration -> zero barrier counters in-graph. The
  // memset's dispatch-end L2 writeback-invalidate also guarantees the zeros
  // (and the poison values) are at the coherence point before k_mega starts.
  hipMemsetAsync(d_ws, 0, 65536, stream);
  k_mega<<<NBLK, NTHR, 0, stream>>>(
      xr, xi, pos_r, pos_i, w_in_r, w_in_i, b_in_r, b_in_i,
      w_out_r, w_out_i, b_out_r, b_out_i, w_p_r, w_p_i, b_p_r, b_p_i,
      bar, mr, mi, ur, ui, l0r, l0i, part, w2, zr, zi, a0r, a0i, aor, aoi,
      (float*)d_out, out_size >= 2 * B_ * E_);
}